// Round 6
// baseline (156.171 us; speedup 1.0000x reference)
//
#include <hip/hip_runtime.h>

#define I_DIM 28
#define H_DIM 64
#define T_DIM 128
#define B_DIM 4096
#define OUT_DIM 10
#define MB 16         // batch rows per block: full 16 MFMA B-columns
#define NTHREADS 512  // 8 waves: 0-3 critical (recurrence+acts), 4-7 helper
                      // (x staging + xw=W_ih*x+b one chunk ahead, via LDS)
#define LOG2E 1.44269504088896340736f

typedef __attribute__((ext_vector_type(8))) short bf16x8;
typedef __attribute__((ext_vector_type(4))) float f32x4;
typedef __attribute__((ext_vector_type(4))) unsigned u32x4;

__device__ __forceinline__ float bfbits2f(unsigned b16) {
    return __builtin_bit_cast(float, b16 << 16);
}
// rne-rounded fp32 bits (bf16 lives in top 16 after the add)
__device__ __forceinline__ unsigned rne_u(float f) {
    unsigned u = __builtin_bit_cast(unsigned, f);
    return u + 0x7FFFu + ((u >> 16) & 1u);
}
// pack two floats -> (bf16(b)<<16)|bf16(a) : 2 rne-adds + 1 v_perm
__device__ __forceinline__ unsigned pack_pair(float a, float b) {
    return __builtin_amdgcn_perm(rne_u(b), rne_u(a), 0x07060302u);
}
__device__ __forceinline__ unsigned f2bf_rne(float f) { return rne_u(f) >> 16; }
__device__ __forceinline__ unsigned ftrunc_bf(float f) {
    return __builtin_bit_cast(unsigned, f) >> 16;
}

// 8 floats -> single rne-bf16 frag (4 dwords)
__device__ __forceinline__ bf16x8 pack_frag(const float* v) {
    u32x4 w;
    #pragma unroll
    for (int i = 0; i < 4; ++i) w[i] = pack_pair(v[2*i], v[2*i+1]);
    return __builtin_bit_cast(bf16x8, w);
}

// 8 floats -> hi/lo bf16 frags (used for W_ih only; startup)
__device__ __forceinline__ void split_frag(const float* v, bf16x8& hi, bf16x8& lo) {
    unsigned hb[8], lb[8];
    #pragma unroll
    for (int j = 0; j < 8; ++j) {
        hb[j] = f2bf_rne(v[j]);
        float rem = v[j] - bfbits2f(hb[j]);
        lb[j] = ftrunc_bf(rem);
    }
    u32x4 hw, lw;
    #pragma unroll
    for (int i = 0; i < 4; ++i) {
        hw[i] = (hb[2*i+1] << 16) | (hb[2*i] & 0xFFFFu);
        lw[i] = (lb[2*i+1] << 16) | (lb[2*i] & 0xFFFFu);
    }
    hi = __builtin_bit_cast(bf16x8, hw);
    lo = __builtin_bit_cast(bf16x8, lw);
}

__device__ __forceinline__ float fast_rcp(float v) { return __builtin_amdgcn_rcpf(v); }
__device__ __forceinline__ float exp2_f(float v)  { return __builtin_amdgcn_exp2f(v); }

// Merged single-rcp LSTM cell update. Preacts LOG2E-scaled; cs is LOG2E*c.
// cc = cs/(1+B) + L(C-1)/((1+A)(C+1))
//    = [cs*(1+A)(C+1) + L(C-1)(1+B)] * rcp((1+B)(1+A)(C+1))   <- ONE rcp
// h  = (E-1) * rcp((1+D)(E+1)),  E = 2^(2cc)
// 5 exp + 2 rcp per cell (was 5+3). Inf-safe for |preact| < 44.
__device__ __forceinline__ float cell_update(float ia, float fa, float ga,
                                             float oa, float& cs) {
    float A  = exp2_f(-ia);
    float B  = exp2_f(-fa);
    float Cc = exp2_f(ga + ga);
    float D  = exp2_f(-oa);
    float oA = 1.0f + A;
    float oB = 1.0f + B;
    float Cp = Cc + 1.0f;
    float t1 = oA * Cp;                          // (1+A)(C+1)
    float t2 = fmaf(Cc, LOG2E, -LOG2E);          // L(C-1)
    float num = fmaf(cs, t1, t2 * oB);
    float R1  = fast_rcp(t1 * oB);
    float cc  = num * R1;
    cs = cc;
    float E  = exp2_f(cc + cc);
    float R2 = fast_rcp((1.0f + D) * (E + 1.0f));
    return (E - 1.0f) * R2;                      // h = sig(o)*tanh(c)
}

#define MFMA(A, B, C) __builtin_amdgcn_mfma_f32_16x16x32_bf16((A), (B), (C), 0, 0, 0)

// Raw barrier with counted wait: LDS writes must be visible (lgkmcnt(0)),
// but global loads (helper x prefetch) stay in flight across the barrier.
#define BAR() do {                                              \
    asm volatile("s_waitcnt lgkmcnt(0)" ::: "memory");          \
    __builtin_amdgcn_s_barrier();                               \
} while (0)

__global__ __launch_bounds__(NTHREADS, 1)
void lstm_mfma_kernel(const float* __restrict__ x,
                      const float* __restrict__ W_ih,
                      const float* __restrict__ W_hh,
                      const float* __restrict__ b_ih,
                      const float* __restrict__ b_hh,
                      const float* __restrict__ W_out,
                      const float* __restrict__ b_out,
                      float* __restrict__ out)
{
    const int tid  = threadIdx.x;
    const int wv   = tid >> 6;        // wave 0..7
    const int rw   = wv & 3;          // role-local wave index 0..3
    const bool helper = wv >= 4;
    const int lane = tid & 63;
    const int q    = lane >> 4;       // quad
    const int cm   = lane & 15;       // batch column (all 16 real)
    const int b0   = blockIdx.x * MB;

    // h state, single rne-bf16, B-frag dword order, double-buffered (4 KB)
    __shared__ __align__(16) unsigned hbuf[2][512];
    // x B-frags, [chunk parity][tt][frag dwords] (8 KB); helpers only
    __shared__ __align__(16) unsigned xbuf[2][2][256];
    // xw = W_ih*x + b, f32 C-frags: [chunk parity][tt][gate][(rw*64+lane)*4] (64 KB)
    __shared__ __align__(16) float    xwbuf[2][2][4][1024];

    // ---- resident A-frags (weights, pre-scaled by LOG2E), per role:
    // gate order in registers: 0=g, 1=i, 2=f, 3=o (g first -> trans chain
    // starts earliest; o needed last).  gmap[] = source gate row block.
    const int gmap[4] = {2, 0, 1, 3};   // g, i, f, o
    bf16x8 Whh[4][2];                 // critical
    bf16x8 Wih_hi[4], Wih_lo[4];      // helper
    f32x4  bias_c[4];                 // helper
    if (!helper) {
        #pragma unroll
        for (int g = 0; g < 4; ++g) {
            const int gn = (rw + 4 * gmap[g]) * 16 + cm;   // global gate row
            #pragma unroll
            for (int kt = 0; kt < 2; ++kt) {
                const float* wr = W_hh + gn * H_DIM + kt * 32 + q * 8;
                float wt[8];
                float4 wa = *(const float4*)wr;
                float4 wb = *(const float4*)(wr + 4);
                wt[0]=wa.x*LOG2E; wt[1]=wa.y*LOG2E; wt[2]=wa.z*LOG2E; wt[3]=wa.w*LOG2E;
                wt[4]=wb.x*LOG2E; wt[5]=wb.y*LOG2E; wt[6]=wb.z*LOG2E; wt[7]=wb.w*LOG2E;
                Whh[g][kt] = pack_frag(wt);
            }
        }
    } else {
        #pragma unroll
        for (int g = 0; g < 4; ++g) {
            const int gn = (rw + 4 * gmap[g]) * 16 + cm;
            const float* ir = W_ih + gn * I_DIM + q * 8;
            float wt[8];
            float4 ia = *(const float4*)ir;
            wt[0]=ia.x*LOG2E; wt[1]=ia.y*LOG2E; wt[2]=ia.z*LOG2E; wt[3]=ia.w*LOG2E;
            if (q < 3) {
                float4 ib = *(const float4*)(ir + 4);
                wt[4]=ib.x*LOG2E; wt[5]=ib.y*LOG2E; wt[6]=ib.z*LOG2E; wt[7]=ib.w*LOG2E;
            } else { wt[4]=0.f; wt[5]=0.f; wt[6]=0.f; wt[7]=0.f; }
            split_frag(wt, Wih_hi[g], Wih_lo[g]);
            #pragma unroll
            for (int r = 0; r < 4; ++r) {
                const int row = gmap[g] * H_DIM + rw * 16 + 4 * q + r;
                bias_c[g][r] = (b_ih[row] + b_hh[row]) * LOG2E;
            }
        }
    }

    // zero h buffers (h0 = 0)
    for (int i = tid; i < 1024; i += NTHREADS)
        ((unsigned*)hbuf)[i] = 0u;

    // ---- helper staging geometry (unchanged from R5)
    const int tts = rw >> 1;
    const int dl  = (rw & 1) * 32 + (lane & 31);  // data-lane 0..63
    const int ps  = lane >> 5;
    const int fo  = (dl >> 4) * 8 + ps * 4;       // float offset 0..28
    const bool sval = fo < I_DIM;                 // fo==28 -> zero pad
    const float* xbase = x + (size_t)(b0 + (dl & 15)) * T_DIM * I_DIM + fo;

    auto load_x4 = [&](int t) -> float4 {
        if (!sval) return float4{0.f, 0.f, 0.f, 0.f};
        return *(const float4*)(xbase + (size_t)t * I_DIM);
    };
    auto pack_store_x = [&](int slot, const float4& v) {
        uint2 pw;
        pw.x = pack_pair(v.x, v.y);
        pw.y = pack_pair(v.z, v.w);
        *(uint2*)&xbuf[slot][tts][dl * 4 + 2 * ps] = pw;
    };

    const int xwt = (rw * 64 + lane) * 4;   // float offset into xwbuf[..][g]

    // ---- prologue: xbuf[0]=x(ch0), xbuf[1]=x(ch1); xw(ch0)->xwbuf[0];
    // xs regs <- x(ch2)
    if (helper) {
        pack_store_x(0, load_x4(tts));
        pack_store_x(1, load_x4(2 + tts));
    }
    __syncthreads();
    float4 xs{0.f, 0.f, 0.f, 0.f};
    if (helper) {
        #pragma unroll
        for (int tt = 0; tt < 2; ++tt) {
            bf16x8 X = __builtin_bit_cast(bf16x8, *(const u32x4*)&xbuf[0][tt][lane * 4]);
            #pragma unroll
            for (int g = 0; g < 4; ++g) {
                f32x4 a = MFMA(Wih_hi[g], X, bias_c[g]);
                a = MFMA(Wih_lo[g], X, a);
                *(f32x4*)&xwbuf[0][tt][g][xwt] = a;
            }
        }
        xs = load_x4(4 + tts);   // x(chunk 2)
    }
    __syncthreads();

    f32x4 c_st = {0.f, 0.f, 0.f, 0.f};   // scaled cell state, 4 cells/lane
    // h write dword: rows rw*16+4q+r, col cm -> b64 of two packed pairs
    const int hdw = 256 * (rw >> 1) + 64 * (2 * (rw & 1) + (q >> 1))
                  + 4 * cm + 2 * (q & 1);

    const f32x4 zeroC = {0.f, 0.f, 0.f, 0.f};

    // one recurrence step given pre-read H frags + xw frags.
    // MFMA order: g split-K (2 independent + add), then i, f (chained), o last.
    auto rec_step = [&](bf16x8 H0, bf16x8 H1, const f32x4* xw, unsigned* hwr) {
        f32x4 acc[4];
        {   // g-gate: split-K, no MFMA->MFMA dependency on the chain entry
            f32x4 a0 = MFMA(Whh[0][0], H0, xw[0]);
            f32x4 b0 = MFMA(Whh[0][1], H1, zeroC);
            acc[0] = a0 + b0;
        }
        #pragma unroll
        for (int g = 1; g < 4; ++g) {
            f32x4 a = MFMA(Whh[g][0], H0, xw[g]);
            a = MFMA(Whh[g][1], H1, a);
            acc[g] = a;
        }
        float hh[4];
        #pragma unroll
        for (int r = 0; r < 4; ++r) {
            float csr = c_st[r];
            // args: (ia, fa, ga, oa) -> regs (1=i, 2=f, 0=g, 3=o)
            hh[r] = cell_update(acc[1][r], acc[2][r], acc[0][r], acc[3][r], csr);
            c_st[r] = csr;
        }
        uint2 hw2;
        hw2.x = pack_pair(hh[0], hh[1]);
        hw2.y = pack_pair(hh[2], hh[3]);
        *(uint2*)&hwr[hdw] = hw2;
    };

    if (!helper) __builtin_amdgcn_s_setprio(1);   // critical wave = long pole

    for (int ch = 0; ch < T_DIM / 2; ++ch) {
        const int p = ch & 1;
        // helper: xbuf[p] <- x(ch+2) (xs regs loaded a chunk ago; the vmcnt
        // wait lands here, long after issue)
        if (helper) pack_store_x(p, xs);
        BAR();   // xw(ch) in xwbuf[p], xbuf writes, prev h writes all visible

        if (!helper) {
            // ---- critical: H frags FIRST (LDS returns in-order; H gates the
            // first MFMA), then xw0, then xw1 (needed only after mid-BAR).
            bf16x8 H0 = __builtin_bit_cast(bf16x8, *(const u32x4*)&hbuf[0][lane * 4]);
            bf16x8 H1 = __builtin_bit_cast(bf16x8, *(const u32x4*)&hbuf[0][256 + lane * 4]);
            f32x4 xw0[4], xw1[4];
            #pragma unroll
            for (int g = 0; g < 4; ++g)
                xw0[g] = *(const f32x4*)&xwbuf[p][0][g][xwt];
            #pragma unroll
            for (int g = 0; g < 4; ++g)
                xw1[g] = *(const f32x4*)&xwbuf[p][1][g][xwt];
            rec_step(H0, H1, xw0, hbuf[1]);
            BAR();   // h(t) visible
            bf16x8 G0 = __builtin_bit_cast(bf16x8, *(const u32x4*)&hbuf[1][lane * 4]);
            bf16x8 G1 = __builtin_bit_cast(bf16x8, *(const u32x4*)&hbuf[1][256 + lane * 4]);
            rec_step(G0, G1, xw1, hbuf[0]);
        } else {
            // ---- helper: xw(ch+1) from xbuf[p^1], written into xwbuf[p^1]
            bf16x8 X0 = __builtin_bit_cast(bf16x8, *(const u32x4*)&xbuf[p ^ 1][0][lane * 4]);
            bf16x8 X1 = __builtin_bit_cast(bf16x8, *(const u32x4*)&xbuf[p ^ 1][1][lane * 4]);
            #pragma unroll
            for (int g = 0; g < 4; ++g) {
                f32x4 a = MFMA(Wih_hi[g], X0, bias_c[g]);
                a = MFMA(Wih_lo[g], X0, a);
                *(f32x4*)&xwbuf[p ^ 1][0][g][xwt] = a;
            }
            int tld = 2 * ch + 6 + tts;          // x for chunk ch+3
            if (tld > T_DIM - 1) tld = T_DIM - 1;
            float4 xs2 = load_x4(tld);
            BAR();   // matches critical's mid-chunk barrier
            #pragma unroll
            for (int g = 0; g < 4; ++g) {
                f32x4 a = MFMA(Wih_hi[g], X1, bias_c[g]);
                a = MFMA(Wih_lo[g], X1, a);
                *(f32x4*)&xwbuf[p ^ 1][1][g][xwt] = a;
            }
            xs = xs2;
        }
    }
    if (!helper) __builtin_amdgcn_s_setprio(0);

    __syncthreads();   // full drain; orders final hbuf[0] writes

    // ---- output head: final h(T) is in hbuf[0] (T even)
    if (tid < MB * OUT_DIM) {
        const int bb = tid / OUT_DIM;
        const int o  = tid % OUT_DIM;
        float s = b_out[o];
        const float* wo = W_out + o * H_DIM;
        #pragma unroll
        for (int u = 0; u < H_DIM; ++u) {
            const int dw = 256 * (u >> 5) + 64 * ((u >> 3) & 3) + 4 * bb + ((u >> 1) & 3);
            const int sh = (u & 1) * 16;
            float h = bfbits2f((hbuf[0][dw] >> sh) & 0xFFFFu);
            s += h * wo[u];
        }
        out[(size_t)(b0 + bb) * OUT_DIM + o] = s;
    }
}

extern "C" void kernel_launch(void* const* d_in, const int* in_sizes, int n_in,
                              void* d_out, int out_size, void* d_ws, size_t ws_size,
                              hipStream_t stream) {
    const float* x     = (const float*)d_in[0];
    const float* W_ih  = (const float*)d_in[1];
    const float* W_hh  = (const float*)d_in[2];
    const float* b_ih  = (const float*)d_in[3];
    const float* b_hh  = (const float*)d_in[4];
    const float* W_out = (const float*)d_in[5];
    const float* b_out = (const float*)d_in[6];
    float* out = (float*)d_out;

    dim3 grid(B_DIM / MB);    // 256 blocks -> 1 per CU
    dim3 block(NTHREADS);     // 8 waves: 4 critical + 4 helper (antiphase)
    lstm_mfma_kernel<<<grid, block, 0, stream>>>(
        x, W_ih, W_hh, b_ih, b_hh, W_out, b_out, out);
}

// Round 7
// 151.631 us; speedup vs baseline: 1.0299x; 1.0299x over previous
//
#include <hip/hip_runtime.h>

#define I_DIM 28
#define H_DIM 64
#define T_DIM 128
#define B_DIM 4096
#define OUT_DIM 10
#define MB 16         // batch rows per block: full 16 MFMA B-columns
#define NTHREADS 512  // 8 SYMMETRIC waves; wave w owns h-rows w*8+2q+{0,1}
#define LOG2E 1.44269504088896340736f

typedef __attribute__((ext_vector_type(8))) short bf16x8;
typedef __attribute__((ext_vector_type(4))) float f32x4;
typedef __attribute__((ext_vector_type(4))) unsigned u32x4;

__device__ __forceinline__ float bfbits2f(unsigned b16) {
    return __builtin_bit_cast(float, b16 << 16);
}
// rne-rounded fp32 bits (bf16 lives in top 16 after the add)
__device__ __forceinline__ unsigned rne_u(float f) {
    unsigned u = __builtin_bit_cast(unsigned, f);
    return u + 0x7FFFu + ((u >> 16) & 1u);
}
// pack two floats -> (bf16(b)<<16)|bf16(a) : 2 rne-adds + 1 v_perm
__device__ __forceinline__ unsigned pack_pair(float a, float b) {
    return __builtin_amdgcn_perm(rne_u(b), rne_u(a), 0x07060302u);
}
__device__ __forceinline__ unsigned f2bf_rne(float f) { return rne_u(f) >> 16; }
__device__ __forceinline__ unsigned ftrunc_bf(float f) {
    return __builtin_bit_cast(unsigned, f) >> 16;
}

// 8 floats -> single rne-bf16 frag (4 dwords)
__device__ __forceinline__ bf16x8 pack_frag(const float* v) {
    u32x4 w;
    #pragma unroll
    for (int i = 0; i < 4; ++i) w[i] = pack_pair(v[2*i], v[2*i+1]);
    return __builtin_bit_cast(bf16x8, w);
}

// 8 floats -> hi/lo bf16 frags (used for W_ih only; startup)
__device__ __forceinline__ void split_frag(const float* v, bf16x8& hi, bf16x8& lo) {
    unsigned hb[8], lb[8];
    #pragma unroll
    for (int j = 0; j < 8; ++j) {
        hb[j] = f2bf_rne(v[j]);
        float rem = v[j] - bfbits2f(hb[j]);
        lb[j] = ftrunc_bf(rem);
    }
    u32x4 hw, lw;
    #pragma unroll
    for (int i = 0; i < 4; ++i) {
        hw[i] = (hb[2*i+1] << 16) | (hb[2*i] & 0xFFFFu);
        lw[i] = (lb[2*i+1] << 16) | (lb[2*i] & 0xFFFFu);
    }
    hi = __builtin_bit_cast(bf16x8, hw);
    lo = __builtin_bit_cast(bf16x8, lw);
}

__device__ __forceinline__ float fast_rcp(float v) { return __builtin_amdgcn_rcpf(v); }
__device__ __forceinline__ float exp2_f(float v)  { return __builtin_amdgcn_exp2f(v); }

// Merged single-rcp LSTM cell update. Preacts LOG2E-scaled; cs is LOG2E*c.
// cc = [cs*(1+A)(C+1) + L(C-1)(1+B)] * rcp((1+B)(1+A)(C+1))
// h  = (E-1) * rcp((1+D)(E+1)),  E = 2^(2cc)
// 5 exp + 2 rcp per cell. Inf-safe for |preact| < 44.
__device__ __forceinline__ float cell_update(float ia, float fa, float ga,
                                             float oa, float& cs) {
    float A  = exp2_f(-ia);
    float B  = exp2_f(-fa);
    float Cc = exp2_f(ga + ga);
    float D  = exp2_f(-oa);
    float oA = 1.0f + A;
    float oB = 1.0f + B;
    float Cp = Cc + 1.0f;
    float t1 = oA * Cp;                          // (1+A)(C+1)
    float t2 = fmaf(Cc, LOG2E, -LOG2E);          // L(C-1)
    float num = fmaf(cs, t1, t2 * oB);
    float R1  = fast_rcp(t1 * oB);
    float cc  = num * R1;
    cs = cc;
    float E  = exp2_f(cc + cc);
    float R2 = fast_rcp((1.0f + D) * (E + 1.0f));
    return (E - 1.0f) * R2;                      // h = sig(o)*tanh(c)
}

#define MFMA(A, B, C) __builtin_amdgcn_mfma_f32_16x16x32_bf16((A), (B), (C), 0, 0, 0)

// Raw barrier with counted wait: LDS writes must be visible (lgkmcnt(0)),
// but global loads (x prefetch) stay in flight across the barrier.
#define BAR() do {                                              \
    asm volatile("s_waitcnt lgkmcnt(0)" ::: "memory");          \
    __builtin_amdgcn_s_barrier();                               \
} while (0)

__global__ __launch_bounds__(NTHREADS, 1)
void lstm_mfma_kernel(const float* __restrict__ x,
                      const float* __restrict__ W_ih,
                      const float* __restrict__ W_hh,
                      const float* __restrict__ b_ih,
                      const float* __restrict__ b_hh,
                      const float* __restrict__ W_out,
                      const float* __restrict__ b_out,
                      float* __restrict__ out)
{
    const int tid  = threadIdx.x;
    const int wv   = tid >> 6;        // wave 0..7 (all symmetric)
    const int lane = tid & 63;
    const int q    = lane >> 4;       // quad
    const int cm   = lane & 15;       // batch column (all 16 real)
    const int b0   = blockIdx.x * MB;

    // h state, single rne-bf16, B-frag dword order, double-buffered (4 KB)
    __shared__ __align__(16) unsigned hbuf[2][512];
    // x B-frags, [chunk parity][tt][frag dwords] (8 KB)
    __shared__ __align__(16) unsigned xbuf[2][2][256];

    // ---- resident A-frags (pre-scaled by LOG2E).
    // Row remap: tile m in {0,1}, A/C-row a (0..15): gate = a&3 (i,f,g,o),
    // h-row = wv*8 + 2*(a>>2) + m.  => lane (q,c), reg r of tile m holds
    // gate r's preact for cell (wv*8+2q+m, c): all 4 gates in-lane, and the
    // lane's two cells are the CONSECUTIVE rows wv*8+2q, wv*8+2q+1.
    bf16x8 Whh[2][2];        // [tile][K-chunk]
    bf16x8 Wih_hi[2], Wih_lo[2];
    f32x4  bias_c[2];
    #pragma unroll
    for (int m = 0; m < 2; ++m) {
        const int arow = (cm & 3) * H_DIM + wv * 8 + 2 * (cm >> 2) + m; // W row
        #pragma unroll
        for (int kt = 0; kt < 2; ++kt) {
            const float* wr = W_hh + arow * H_DIM + kt * 32 + q * 8;
            float wt[8];
            float4 wa = *(const float4*)wr;
            float4 wb = *(const float4*)(wr + 4);
            wt[0]=wa.x*LOG2E; wt[1]=wa.y*LOG2E; wt[2]=wa.z*LOG2E; wt[3]=wa.w*LOG2E;
            wt[4]=wb.x*LOG2E; wt[5]=wb.y*LOG2E; wt[6]=wb.z*LOG2E; wt[7]=wb.w*LOG2E;
            Whh[m][kt] = pack_frag(wt);
        }
        {
            const float* ir = W_ih + arow * I_DIM + q * 8;
            float wt[8];
            float4 ia = *(const float4*)ir;
            wt[0]=ia.x*LOG2E; wt[1]=ia.y*LOG2E; wt[2]=ia.z*LOG2E; wt[3]=ia.w*LOG2E;
            if (q < 3) {
                float4 ib = *(const float4*)(ir + 4);
                wt[4]=ib.x*LOG2E; wt[5]=ib.y*LOG2E; wt[6]=ib.z*LOG2E; wt[7]=ib.w*LOG2E;
            } else { wt[4]=0.f; wt[5]=0.f; wt[6]=0.f; wt[7]=0.f; }
            split_frag(wt, Wih_hi[m], Wih_lo[m]);
        }
        #pragma unroll
        for (int r = 0; r < 4; ++r) {
            const int row = r * H_DIM + wv * 8 + 2 * q + m;
            bias_c[m][r] = (b_ih[row] + b_hh[row]) * LOG2E;
        }
    }

    // zero h buffers (h0 = 0)
    for (int i = tid; i < 1024; i += NTHREADS)
        ((unsigned*)hbuf)[i] = 0u;

    // ---- x staging (waves 0-3 only; 1 float4 load + 2 packs + b64 write
    // per lane per chunk). Wave w stages timestep (w>>1), half (w&1) lanes.
    const int tts = wv >> 1;
    const int dl  = (wv & 1) * 32 + (lane & 31);  // data-lane 0..63
    const int ps  = lane >> 5;
    const int fo  = (dl >> 4) * 8 + ps * 4;       // float offset 0..28
    const bool sval = fo < I_DIM;                 // fo==28 -> zero pad
    const float* xbase = x + (size_t)(b0 + (dl & 15)) * T_DIM * I_DIM + fo;

    auto load_x4 = [&](int t) -> float4 {
        if (!sval) return float4{0.f, 0.f, 0.f, 0.f};
        return *(const float4*)(xbase + (size_t)t * I_DIM);
    };
    auto pack_store_x = [&](int slot, const float4& v) {
        uint2 pw;
        pw.x = pack_pair(v.x, v.y);
        pw.y = pack_pair(v.z, v.w);
        *(uint2*)&xbuf[slot][tts][dl * 4 + 2 * ps] = pw;
    };

    // ---- prologue: xbuf[0]=x(ch0), xbuf[1]=x(ch1); xw(ch0) in regs;
    // xs <- x(ch2)
    if (wv < 4) {
        pack_store_x(0, load_x4(tts));
        pack_store_x(1, load_x4(2 + tts));
    }
    __syncthreads();

    f32x4 xwA[4], xwB[4];   // [tt*2+m], ping-ponged across chunks
    {
        bf16x8 Xa = __builtin_bit_cast(bf16x8, *(const u32x4*)&xbuf[0][0][lane * 4]);
        bf16x8 Xb = __builtin_bit_cast(bf16x8, *(const u32x4*)&xbuf[0][1][lane * 4]);
        #pragma unroll
        for (int m = 0; m < 2; ++m) {
            f32x4 a = MFMA(Wih_hi[m], Xa, bias_c[m]);
            a = MFMA(Wih_lo[m], Xa, a);
            xwA[m] = a;
            f32x4 b = MFMA(Wih_hi[m], Xb, bias_c[m]);
            b = MFMA(Wih_lo[m], Xb, b);
            xwA[2 + m] = b;
        }
    }
    float4 xs{0.f, 0.f, 0.f, 0.f};
    if (wv < 4) xs = load_x4(4 + tts);   // x(chunk 2)
    __syncthreads();   // xbuf[0] reads drained before ch0 overwrites it

    float2 c_st = {0.f, 0.f};   // scaled cell state (LOG2E*c) for the 2 cells
    // h write dword: row-pair rp = wv*4+q, batch cm
    const int hdw = 256 * (wv >> 2) + 64 * (wv & 3) + 4 * cm + q;

    // one recurrence step; also computes next chunk's xw for this tt (off-chain
    // MFMAs fill the pipe while the activation chain runs)
    auto rec_step = [&](const unsigned* hrd, unsigned* hwr,
                        f32x4 xw0, f32x4 xw1, bf16x8 X,
                        f32x4& xn0, f32x4& xn1) {
        bf16x8 H0 = __builtin_bit_cast(bf16x8, *(const u32x4*)&hrd[lane * 4]);
        bf16x8 H1 = __builtin_bit_cast(bf16x8, *(const u32x4*)&hrd[256 + lane * 4]);
        f32x4 a0 = MFMA(Whh[0][0], H0, xw0);
        f32x4 a1 = MFMA(Whh[1][0], H0, xw1);
        a0 = MFMA(Whh[0][1], H1, a0);
        a1 = MFMA(Whh[1][1], H1, a1);
        // next-chunk xw (independent)
        f32x4 n0 = MFMA(Wih_hi[0], X, bias_c[0]);
        f32x4 n1 = MFMA(Wih_hi[1], X, bias_c[1]);
        n0 = MFMA(Wih_lo[0], X, n0);
        n1 = MFMA(Wih_lo[1], X, n1);
        xn0 = n0; xn1 = n1;
        float h0 = cell_update(a0[0], a0[1], a0[2], a0[3], c_st.x);
        float h1 = cell_update(a1[0], a1[1], a1[2], a1[3], c_st.y);
        hwr[hdw] = pack_pair(h0, h1);   // rows (wv*8+2q, wv*8+2q+1), batch cm
    };

    auto chunk_body = [&](int ch, f32x4 (&xwC)[4], f32x4 (&xwN)[4]) {
        const int p = ch & 1;
        if (wv < 4) pack_store_x(p, xs);   // x(ch+2); vmcnt wait lands here
        BAR();   // xbuf(ch+1..2) + prev h writes visible

        // X frags for xw(ch+1): BOTH read before the mid barrier so next
        // chunk's staging writes (after my BAR2-drained reads) can't race.
        bf16x8 X0 = __builtin_bit_cast(bf16x8, *(const u32x4*)&xbuf[p ^ 1][0][lane * 4]);
        bf16x8 X1 = __builtin_bit_cast(bf16x8, *(const u32x4*)&xbuf[p ^ 1][1][lane * 4]);

        rec_step(hbuf[0], hbuf[1], xwC[0], xwC[1], X0, xwN[0], xwN[1]);

        // issue x(ch+3) load; stays in flight across barriers
        float4 xs2{0.f, 0.f, 0.f, 0.f};
        if (wv < 4) {
            int tld = 2 * ch + 6 + tts;
            if (tld > T_DIM - 1) tld = T_DIM - 1;
            xs2 = load_x4(tld);
        }
        BAR();   // h(t0) visible
        rec_step(hbuf[1], hbuf[0], xwC[2], xwC[3], X1, xwN[2], xwN[3]);
        xs = xs2;
    };

    for (int ch = 0; ch < T_DIM / 2; ch += 2) {
        chunk_body(ch,     xwA, xwB);   // ping-pong: no xw copy movs
        chunk_body(ch + 1, xwB, xwA);
    }

    __syncthreads();   // full drain; orders final hbuf[0] writes

    // ---- output head: final h(T) is in hbuf[0] (T even); layout unchanged
    if (tid < MB * OUT_DIM) {
        const int bb = tid / OUT_DIM;
        const int o  = tid % OUT_DIM;
        float s = b_out[o];
        const float* wo = W_out + o * H_DIM;
        #pragma unroll
        for (int u = 0; u < H_DIM; ++u) {
            const int dw = 256 * (u >> 5) + 64 * ((u >> 3) & 3) + 4 * bb + ((u >> 1) & 3);
            const int sh = (u & 1) * 16;
            float h = bfbits2f((hbuf[0][dw] >> sh) & 0xFFFFu);
            s += h * wo[u];
        }
        out[(size_t)(b0 + bb) * OUT_DIM + o] = s;
    }
}

extern "C" void kernel_launch(void* const* d_in, const int* in_sizes, int n_in,
                              void* d_out, int out_size, void* d_ws, size_t ws_size,
                              hipStream_t stream) {
    const float* x     = (const float*)d_in[0];
    const float* W_ih  = (const float*)d_in[1];
    const float* W_hh  = (const float*)d_in[2];
    const float* b_ih  = (const float*)d_in[3];
    const float* b_hh  = (const float*)d_in[4];
    const float* W_out = (const float*)d_in[5];
    const float* b_out = (const float*)d_in[6];
    float* out = (float*)d_out;

    dim3 grid(B_DIM / MB);    // 256 blocks -> 1 per CU
    dim3 block(NTHREADS);     // 8 symmetric waves = 2/SIMD, each 1/8 of chain
    lstm_mfma_kernel<<<grid, block, 0, stream>>>(
        x, W_ih, W_hh, b_ih, b_hh, W_out, b_out, out);
}

// Round 8
// 144.393 us; speedup vs baseline: 1.0816x; 1.0501x over previous
//
#include <hip/hip_runtime.h>

#define I_DIM 28
#define H_DIM 64
#define T_DIM 128
#define B_DIM 4096
#define OUT_DIM 10
#define MB 16         // batch rows per block: full 16 MFMA B-columns
#define NTHREADS 512  // 8 SYMMETRIC waves; wave w owns h-rows w*8+2q+{0,1}
                      // SIMD siblings (w, w+4) run mirrored schedules (P/Q)
#define LOG2E 1.44269504088896340736f

typedef __attribute__((ext_vector_type(8))) short bf16x8;
typedef __attribute__((ext_vector_type(4))) float f32x4;
typedef __attribute__((ext_vector_type(4))) unsigned u32x4;

__device__ __forceinline__ float bfbits2f(unsigned b16) {
    return __builtin_bit_cast(float, b16 << 16);
}
// rne-rounded fp32 bits (bf16 lives in top 16 after the add)
__device__ __forceinline__ unsigned rne_u(float f) {
    unsigned u = __builtin_bit_cast(unsigned, f);
    return u + 0x7FFFu + ((u >> 16) & 1u);
}
// pack two floats -> (bf16(b)<<16)|bf16(a) : 2 rne-adds + 1 v_perm
__device__ __forceinline__ unsigned pack_pair(float a, float b) {
    return __builtin_amdgcn_perm(rne_u(b), rne_u(a), 0x07060302u);
}
__device__ __forceinline__ unsigned f2bf_rne(float f) { return rne_u(f) >> 16; }
__device__ __forceinline__ unsigned ftrunc_bf(float f) {
    return __builtin_bit_cast(unsigned, f) >> 16;
}

// 8 floats -> single rne-bf16 frag (4 dwords)
__device__ __forceinline__ bf16x8 pack_frag(const float* v) {
    u32x4 w;
    #pragma unroll
    for (int i = 0; i < 4; ++i) w[i] = pack_pair(v[2*i], v[2*i+1]);
    return __builtin_bit_cast(bf16x8, w);
}

// 8 floats -> hi/lo bf16 frags (used for W_ih only; startup)
__device__ __forceinline__ void split_frag(const float* v, bf16x8& hi, bf16x8& lo) {
    unsigned hb[8], lb[8];
    #pragma unroll
    for (int j = 0; j < 8; ++j) {
        hb[j] = f2bf_rne(v[j]);
        float rem = v[j] - bfbits2f(hb[j]);
        lb[j] = ftrunc_bf(rem);
    }
    u32x4 hw, lw;
    #pragma unroll
    for (int i = 0; i < 4; ++i) {
        hw[i] = (hb[2*i+1] << 16) | (hb[2*i] & 0xFFFFu);
        lw[i] = (lb[2*i+1] << 16) | (lb[2*i] & 0xFFFFu);
    }
    hi = __builtin_bit_cast(bf16x8, hw);
    lo = __builtin_bit_cast(bf16x8, lw);
}

__device__ __forceinline__ float fast_rcp(float v) { return __builtin_amdgcn_rcpf(v); }
__device__ __forceinline__ float exp2_f(float v)  { return __builtin_amdgcn_exp2f(v); }

// Merged single-rcp LSTM cell update. Preacts LOG2E-scaled; cs is LOG2E*c.
// cc = [cs*(1+A)(C+1) + L(C-1)(1+B)] * rcp((1+B)(1+A)(C+1))
// h  = (E-1) * rcp((1+D)(E+1)),  E = 2^(2cc)
// 5 exp + 2 rcp per cell. Inf-safe for |preact| < 44.
__device__ __forceinline__ float cell_update(float ia, float fa, float ga,
                                             float oa, float& cs) {
    float A  = exp2_f(-ia);
    float B  = exp2_f(-fa);
    float Cc = exp2_f(ga + ga);
    float D  = exp2_f(-oa);
    float oA = 1.0f + A;
    float oB = 1.0f + B;
    float Cp = Cc + 1.0f;
    float t1 = oA * Cp;                          // (1+A)(C+1)
    float t2 = fmaf(Cc, LOG2E, -LOG2E);          // L(C-1)
    float num = fmaf(cs, t1, t2 * oB);
    float R1  = fast_rcp(t1 * oB);
    float cc  = num * R1;
    cs = cc;
    float E  = exp2_f(cc + cc);
    float R2 = fast_rcp((1.0f + D) * (E + 1.0f));
    return (E - 1.0f) * R2;                      // h = sig(o)*tanh(c)
}

#define MFMA(A, B, C) __builtin_amdgcn_mfma_f32_16x16x32_bf16((A), (B), (C), 0, 0, 0)

// Raw barrier with counted wait: LDS writes must be visible (lgkmcnt(0)),
// but global loads (x prefetch) stay in flight across the barrier.
#define BAR() do {                                              \
    asm volatile("s_waitcnt lgkmcnt(0)" ::: "memory");          \
    __builtin_amdgcn_s_barrier();                               \
} while (0)

__global__ __launch_bounds__(NTHREADS, 1)
void lstm_mfma_kernel(const float* __restrict__ x,
                      const float* __restrict__ W_ih,
                      const float* __restrict__ W_hh,
                      const float* __restrict__ b_ih,
                      const float* __restrict__ b_hh,
                      const float* __restrict__ W_out,
                      const float* __restrict__ b_out,
                      float* __restrict__ out)
{
    const int tid  = threadIdx.x;
    const int wv   = tid >> 6;        // wave 0..7 (all symmetric work split)
    const int lane = tid & 63;
    const int q    = lane >> 4;       // quad
    const int cm   = lane & 15;       // batch column (all 16 real)
    const int b0   = blockIdx.x * MB;

    // h state, single rne-bf16, B-frag dword order, double-buffered (4 KB)
    __shared__ __align__(16) unsigned hbuf[2][512];
    // x B-frags, [chunk parity][tt][frag dwords] (8 KB)
    __shared__ __align__(16) unsigned xbuf[2][2][256];

    // ---- resident A-frags (pre-scaled by LOG2E).
    // Row remap: tile m in {0,1}, A/C-row a (0..15): gate = a&3 (i,f,g,o),
    // h-row = wv*8 + 2*(a>>2) + m.  => lane (q,c), reg r of tile m holds
    // gate r's preact for cell (wv*8+2q+m, c): all 4 gates in-lane, and the
    // lane's two cells are the CONSECUTIVE rows wv*8+2q, wv*8+2q+1.
    bf16x8 Whh[2][2];        // [tile][K-chunk]
    bf16x8 Wih_hi[2], Wih_lo[2];
    f32x4  bias_c[2];
    #pragma unroll
    for (int m = 0; m < 2; ++m) {
        const int arow = (cm & 3) * H_DIM + wv * 8 + 2 * (cm >> 2) + m; // W row
        #pragma unroll
        for (int kt = 0; kt < 2; ++kt) {
            const float* wr = W_hh + arow * H_DIM + kt * 32 + q * 8;
            float wt[8];
            float4 wa = *(const float4*)wr;
            float4 wb = *(const float4*)(wr + 4);
            wt[0]=wa.x*LOG2E; wt[1]=wa.y*LOG2E; wt[2]=wa.z*LOG2E; wt[3]=wa.w*LOG2E;
            wt[4]=wb.x*LOG2E; wt[5]=wb.y*LOG2E; wt[6]=wb.z*LOG2E; wt[7]=wb.w*LOG2E;
            Whh[m][kt] = pack_frag(wt);
        }
        {
            const float* ir = W_ih + arow * I_DIM + q * 8;
            float wt[8];
            float4 ia = *(const float4*)ir;
            wt[0]=ia.x*LOG2E; wt[1]=ia.y*LOG2E; wt[2]=ia.z*LOG2E; wt[3]=ia.w*LOG2E;
            if (q < 3) {
                float4 ib = *(const float4*)(ir + 4);
                wt[4]=ib.x*LOG2E; wt[5]=ib.y*LOG2E; wt[6]=ib.z*LOG2E; wt[7]=ib.w*LOG2E;
            } else { wt[4]=0.f; wt[5]=0.f; wt[6]=0.f; wt[7]=0.f; }
            split_frag(wt, Wih_hi[m], Wih_lo[m]);
        }
        #pragma unroll
        for (int r = 0; r < 4; ++r) {
            const int row = r * H_DIM + wv * 8 + 2 * q + m;
            bias_c[m][r] = (b_ih[row] + b_hh[row]) * LOG2E;
        }
    }

    // zero h buffers (h0 = 0)
    for (int i = tid; i < 1024; i += NTHREADS)
        ((unsigned*)hbuf)[i] = 0u;

    // ---- x staging (waves 0-3 only; 1 float4 load + 2 packs + b64 write
    // per lane per chunk). Wave w stages timestep (w>>1), half (w&1) lanes.
    const int tts = wv >> 1;
    const int dl  = (wv & 1) * 32 + (lane & 31);  // data-lane 0..63
    const int ps  = lane >> 5;
    const int fo  = (dl >> 4) * 8 + ps * 4;       // float offset 0..28
    const bool sval = fo < I_DIM;                 // fo==28 -> zero pad
    const float* xbase = x + (size_t)(b0 + (dl & 15)) * T_DIM * I_DIM + fo;

    auto load_x4 = [&](int t) -> float4 {
        if (!sval) return float4{0.f, 0.f, 0.f, 0.f};
        return *(const float4*)(xbase + (size_t)t * I_DIM);
    };
    auto pack_store_x = [&](int slot, const float4& v) {
        uint2 pw;
        pw.x = pack_pair(v.x, v.y);
        pw.y = pack_pair(v.z, v.w);
        *(uint2*)&xbuf[slot][tts][dl * 4 + 2 * ps] = pw;
    };

    // ---- prologue: xbuf[0]=x(ch0), xbuf[1]=x(ch1); xw(ch0) in regs;
    // xs <- x(ch2)
    if (wv < 4) {
        pack_store_x(0, load_x4(tts));
        pack_store_x(1, load_x4(2 + tts));
    }
    __syncthreads();

    f32x4 xwA[4], xwB[4];   // [tt*2+m], ping-ponged across chunks
    {
        bf16x8 Xa = __builtin_bit_cast(bf16x8, *(const u32x4*)&xbuf[0][0][lane * 4]);
        bf16x8 Xb = __builtin_bit_cast(bf16x8, *(const u32x4*)&xbuf[0][1][lane * 4]);
        #pragma unroll
        for (int m = 0; m < 2; ++m) {
            f32x4 a = MFMA(Wih_hi[m], Xa, bias_c[m]);
            a = MFMA(Wih_lo[m], Xa, a);
            xwA[m] = a;
            f32x4 b = MFMA(Wih_hi[m], Xb, bias_c[m]);
            b = MFMA(Wih_lo[m], Xb, b);
            xwA[2 + m] = b;
        }
    }
    float4 xs{0.f, 0.f, 0.f, 0.f};
    if (wv < 4) xs = load_x4(4 + tts);   // x(chunk 2)
    __syncthreads();   // xbuf[0] reads drained before ch0 overwrites it

    float2 c_st = {0.f, 0.f};   // scaled cell state (LOG2E*c) for the 2 cells
    // h write dword: row-pair rp = wv*4+q, batch cm
    const int hdw = 256 * (wv >> 2) + 64 * (wv & 3) + 4 * cm + q;

    // one recurrence step; also computes next chunk's xw for this tt.
    // SIMD siblings (w, w+4) run MIRRORED section orders so on each SIMD one
    // wave feeds the MFMA pipe while the other feeds the trans (exp/rcp) pipe:
    //   P (wv<4):  rec-MFMA -> xw-MFMA -> acts
    //   Q (wv>=4): rec-MFMA -> acts   -> xw-MFMA
    auto rec_step = [&](const unsigned* hrd, unsigned* hwr,
                        f32x4 xw0, f32x4 xw1, bf16x8 X,
                        f32x4& xn0, f32x4& xn1) {
        bf16x8 H0 = __builtin_bit_cast(bf16x8, *(const u32x4*)&hrd[lane * 4]);
        bf16x8 H1 = __builtin_bit_cast(bf16x8, *(const u32x4*)&hrd[256 + lane * 4]);
        f32x4 a0 = MFMA(Whh[0][0], H0, xw0);
        f32x4 a1 = MFMA(Whh[1][0], H0, xw1);
        a0 = MFMA(Whh[0][1], H1, a0);
        a1 = MFMA(Whh[1][1], H1, a1);
        if (wv < 4) {
            // P: xw MFMAs (matrix pipe) while sibling Q runs acts (trans pipe)
            f32x4 n0 = MFMA(Wih_hi[0], X, bias_c[0]);
            f32x4 n1 = MFMA(Wih_hi[1], X, bias_c[1]);
            n0 = MFMA(Wih_lo[0], X, n0);
            n1 = MFMA(Wih_lo[1], X, n1);
            xn0 = n0; xn1 = n1;
            __builtin_amdgcn_sched_barrier(0);
            float h0 = cell_update(a0[0], a0[1], a0[2], a0[3], c_st.x);
            float h1 = cell_update(a1[0], a1[1], a1[2], a1[3], c_st.y);
            hwr[hdw] = pack_pair(h0, h1);
        } else {
            // Q: acts first (h lands early), xw MFMAs fill the tail
            float h0 = cell_update(a0[0], a0[1], a0[2], a0[3], c_st.x);
            float h1 = cell_update(a1[0], a1[1], a1[2], a1[3], c_st.y);
            hwr[hdw] = pack_pair(h0, h1);
            __builtin_amdgcn_sched_barrier(0);
            f32x4 n0 = MFMA(Wih_hi[0], X, bias_c[0]);
            f32x4 n1 = MFMA(Wih_hi[1], X, bias_c[1]);
            n0 = MFMA(Wih_lo[0], X, n0);
            n1 = MFMA(Wih_lo[1], X, n1);
            xn0 = n0; xn1 = n1;
        }
    };

    auto chunk_body = [&](int ch, f32x4 (&xwC)[4], f32x4 (&xwN)[4]) {
        const int p = ch & 1;
        if (wv < 4) pack_store_x(p, xs);   // x(ch+2); vmcnt wait lands here
        BAR();   // xbuf(ch+1..2) + prev h writes visible

        // X frags for xw(ch+1): BOTH read before the mid barrier so next
        // chunk's staging writes (ordered after our lgkmcnt(0)) can't race.
        bf16x8 X0 = __builtin_bit_cast(bf16x8, *(const u32x4*)&xbuf[p ^ 1][0][lane * 4]);
        bf16x8 X1 = __builtin_bit_cast(bf16x8, *(const u32x4*)&xbuf[p ^ 1][1][lane * 4]);

        rec_step(hbuf[0], hbuf[1], xwC[0], xwC[1], X0, xwN[0], xwN[1]);

        // issue x(ch+3) load; stays in flight across barriers
        float4 xs2{0.f, 0.f, 0.f, 0.f};
        if (wv < 4) {
            int tld = 2 * ch + 6 + tts;
            if (tld > T_DIM - 1) tld = T_DIM - 1;
            xs2 = load_x4(tld);
        }
        BAR();   // h(t0) visible
        rec_step(hbuf[1], hbuf[0], xwC[2], xwC[3], X1, xwN[2], xwN[3]);
        xs = xs2;
    };

    for (int ch = 0; ch < T_DIM / 2; ch += 2) {
        chunk_body(ch,     xwA, xwB);   // ping-pong: no xw copy movs
        chunk_body(ch + 1, xwB, xwA);
    }

    __syncthreads();   // full drain; orders final hbuf[0] writes

    // ---- output head: final h(T) is in hbuf[0] (T even); layout unchanged
    if (tid < MB * OUT_DIM) {
        const int bb = tid / OUT_DIM;
        const int o  = tid % OUT_DIM;
        float s = b_out[o];
        const float* wo = W_out + o * H_DIM;
        #pragma unroll
        for (int u = 0; u < H_DIM; ++u) {
            const int dw = 256 * (u >> 5) + 64 * ((u >> 3) & 3) + 4 * bb + ((u >> 1) & 3);
            const int sh = (u & 1) * 16;
            float h = bfbits2f((hbuf[0][dw] >> sh) & 0xFFFFu);
            s += h * wo[u];
        }
        out[(size_t)(b0 + bb) * OUT_DIM + o] = s;
    }
}

extern "C" void kernel_launch(void* const* d_in, const int* in_sizes, int n_in,
                              void* d_out, int out_size, void* d_ws, size_t ws_size,
                              hipStream_t stream) {
    const float* x     = (const float*)d_in[0];
    const float* W_ih  = (const float*)d_in[1];
    const float* W_hh  = (const float*)d_in[2];
    const float* b_ih  = (const float*)d_in[3];
    const float* b_hh  = (const float*)d_in[4];
    const float* W_out = (const float*)d_in[5];
    const float* b_out = (const float*)d_in[6];
    float* out = (float*)d_out;

    dim3 grid(B_DIM / MB);    // 256 blocks -> 1 per CU
    dim3 block(NTHREADS);     // 8 waves = 2/SIMD, mirrored P/Q schedules
    lstm_mfma_kernel<<<grid, block, 0, stream>>>(
        x, W_ih, W_hh, b_ih, b_hh, W_out, b_out, out);
}